// Round 3
// baseline (1920.342 us; speedup 1.0000x reference)
//
#include <hip/hip_runtime.h>

typedef __attribute__((ext_vector_type(4))) float f32x4;
typedef __attribute__((ext_vector_type(8))) short s16x8;

#define N_NODES 65536
#define GNPG 1024
#define FDIM 64
#define HDIM 128
#define KNN 16
#define CAND 24
#define NEDGE (N_NODES * KNN)

__device__ __forceinline__ unsigned short f2bf(float f) {
  union { float f; unsigned int u; } v; v.f = f;
  unsigned int r = v.u + 0x7FFFu + ((v.u >> 16) & 1u);
  return (unsigned short)(r >> 16);
}
__device__ __forceinline__ float bf2f(unsigned short u) {
  union { unsigned int u; float f; } v; v.u = ((unsigned int)u) << 16;
  return v.f;
}

// Build MFMA B-fragment-ordered hi/lo bf16 split of W2 (128x128).
// Frag layout (16x16x32 bf16): lane l holds B[k = 8*(l>>4)+j + 32*ks][col = ct*16 + (l&15)], j=0..7.
__global__ void prep_weights_k(const float* __restrict__ W2,
                               unsigned short* __restrict__ w2h, unsigned short* __restrict__ w2l) {
  int tid = threadIdx.x;
  for (int idx = tid; idx < 8 * 4 * 64 * 8; idx += 256) {
    int j = idx & 7, l = (idx >> 3) & 63, ks = (idx >> 9) & 3, ct = idx >> 11;
    int k = 8 * (l >> 4) + j + 32 * ks, col = ct * 16 + (l & 15);
    float v = W2[k * 128 + col];
    unsigned short hi = f2bf(v);
    w2h[idx] = hi;
    w2l[idx] = f2bf(v - bf2f(hi));
  }
}

// sq in f64 (exact reference-side values) + f32 copy for the candidate pass.
__global__ void prep_sq_k(const float* __restrict__ x, float* __restrict__ sq,
                          double* __restrict__ sq64) {
  int n = blockIdx.x * 256 + threadIdx.x;
  const f32x4* xp = (const f32x4*)(x + (size_t)n * FDIM);
  double s0 = 0, s1 = 0, s2 = 0, s3 = 0;
#pragma unroll
  for (int f = 0; f < 16; ++f) {
    f32x4 a = xp[f];
    s0 = fma((double)a[0], (double)a[0], s0);
    s1 = fma((double)a[1], (double)a[1], s1);
    s2 = fma((double)a[2], (double)a[2], s2);
    s3 = fma((double)a[3], (double)a[3], s3);
  }
  double s = (s0 + s1) + (s2 + s3);
  sq64[n] = s;
  sq[n] = (float)s;
}

// Full-fp32 GEMM1: PQ[n][0:128] = x[n]@(W1_top - W1_bot); PQ[n][128:256] = x[n]@W1_bot + b1.
// Block = 16 nodes; Wc (64x256 f32, 64KB) staged in LDS; 16 threads/node x 16 cols each.
__global__ __launch_bounds__(256) void prep_pq_k(const float* __restrict__ x,
                                                 const float* __restrict__ W1,
                                                 const float* __restrict__ b1,
                                                 float* __restrict__ PQ) {
  __shared__ float WcL[64 * 256];   // 64KB
  __shared__ float xL[16 * 64];     // 4KB
  int tid = threadIdx.x;
  for (int i = tid; i < 64 * 256; i += 256) {
    int k = i >> 8, c = i & 255;
    WcL[i] = (c < 128) ? (W1[k * 128 + c] - W1[(k + 64) * 128 + c])
                       : W1[(k + 64) * 128 + (c - 128)];
  }
  int nbase = blockIdx.x * 16;
  for (int i = tid; i < 16 * 64; i += 256) xL[i] = x[(size_t)nbase * 64 + i];
  __syncthreads();
  int nl = tid >> 4, c0 = tid & 15;
  float acc[16];
#pragma unroll
  for (int j = 0; j < 16; ++j) acc[j] = 0.f;
  for (int k = 0; k < 64; ++k) {
    float xk = xL[nl * 64 + k];
    const float* wr = WcL + k * 256 + c0;
#pragma unroll
    for (int j = 0; j < 16; ++j) acc[j] = fmaf(xk, wr[16 * j], acc[j]);
  }
#pragma unroll
  for (int j = 0; j < 16; ++j) {
    int c = c0 + 16 * j;
    float b = (c >= 128) ? b1[c - 128] : 0.f;
    PQ[(size_t)(nbase + nl) * 256 + c] = acc[j] + b;
  }
}

// One thread per center. Stage 1: fp32 distances, register top-24 superset (insertion,
// strict <). Stage 2: exact f64 re-rank of the 24 candidates (matches the f64 golden ref;
// index tie-break), via fully-unrolled selection sort (compile-time indices only).
__global__ __launch_bounds__(256) void knn_k(const float* __restrict__ x, const float* __restrict__ sq,
                                             const double* __restrict__ sq64,
                                             int* __restrict__ nbr, int* __restrict__ counts) {
  int n = blockIdx.x * 256 + threadIdx.x;
  int base = (n >> 10) << 10;
  f32x4 xi[16];
  const f32x4* xp = (const f32x4*)(x + (size_t)n * FDIM);
#pragma unroll
  for (int f = 0; f < 16; ++f) xi[f] = xp[f];
  float sqi = sq[n];
  float dl[CAND]; int il[CAND];
#pragma unroll
  for (int q = 0; q < CAND; ++q) { dl[q] = 3.0e38f; il[q] = -1; }
#pragma unroll 2
  for (int jl = 0; jl < GNPG; ++jl) {
    int j = base + jl;
    const f32x4* xj = (const f32x4*)(x + (size_t)j * FDIM);
    float s0 = 0, s1 = 0, s2 = 0, s3 = 0;
#pragma unroll
    for (int f = 0; f < 16; ++f) {
      f32x4 a = xi[f], b = xj[f];
      s0 = fmaf(a[0], b[0], s0); s1 = fmaf(a[1], b[1], s1);
      s2 = fmaf(a[2], b[2], s2); s3 = fmaf(a[3], b[3], s3);
    }
    float dot = (s0 + s1) + (s2 + s3);
    float d = sqi + sq[j] - 2.f * dot;
    if (j != n && d < dl[CAND - 1]) {
      dl[CAND - 1] = d; il[CAND - 1] = j;
#pragma unroll
      for (int p = CAND - 1; p >= 1; --p) {
        float a0 = dl[p - 1], a1 = dl[p];
        int b0 = il[p - 1], b1v = il[p];
        bool c = a1 < a0;
        dl[p - 1] = c ? a1 : a0; dl[p] = c ? a0 : a1;
        il[p - 1] = c ? b1v : b0; il[p] = c ? b0 : b1v;
      }
    }
  }
  // Stage 2: exact f64 distances for the 24 candidates.
  double d64[CAND];
  double sq64i = sq64[n];
  for (int q = 0; q < CAND; ++q) {
    int j = il[q];
    const f32x4* xj = (const f32x4*)(x + (size_t)j * FDIM);
    double s0 = 0, s1 = 0, s2 = 0, s3 = 0;
#pragma unroll
    for (int f = 0; f < 16; ++f) {
      f32x4 a = xi[f], b = xj[f];
      s0 = fma((double)a[0], (double)b[0], s0);
      s1 = fma((double)a[1], (double)b[1], s1);
      s2 = fma((double)a[2], (double)b[2], s2);
      s3 = fma((double)a[3], (double)b[3], s3);
    }
    d64[q] = sq64i + sq64[j] - 2.0 * ((s0 + s1) + (s2 + s3));
  }
  // Fully-unrolled selection sort of first KNN positions by (d64, index).
#pragma unroll
  for (int a = 0; a < KNN; ++a)
#pragma unroll
    for (int b = a + 1; b < CAND; ++b) {
      bool sw = (d64[b] < d64[a]) || (d64[b] == d64[a] && il[b] < il[a]);
      double td = sw ? d64[b] : d64[a];
      double tu = sw ? d64[a] : d64[b];
      int ti = sw ? il[b] : il[a];
      int tv = sw ? il[a] : il[b];
      d64[a] = td; d64[b] = tu; il[a] = ti; il[b] = tv;
    }
#pragma unroll
  for (int q = 0; q < KNN; ++q) {
    int id = il[q];
    nbr[(size_t)n * KNN + q] = id;
    atomicAdd(&counts[id], 1);
  }
}

__global__ void scan_k(const int* __restrict__ counts, int* __restrict__ cursor) {
  __shared__ int part[256];
  int t = threadIdx.x, base = t * 256;
  int s = 0;
  for (int i = 0; i < 256; ++i) s += counts[base + i];
  part[t] = s;
  __syncthreads();
  if (t == 0) {
    int run = 0;
    for (int i = 0; i < 256; ++i) { int v = part[i]; part[i] = run; run += v; }
  }
  __syncthreads();
  int run = part[t];
  for (int i = 0; i < 256; ++i) { int idx = base + i; cursor[idx] = run; run += counts[idx]; }
}

__global__ void scatter_k(const int* __restrict__ nbr, int* __restrict__ cursor,
                          int* __restrict__ srow, int* __restrict__ scol) {
  int e = blockIdx.x * 256 + threadIdx.x;
  int r = nbr[e], c = e >> 4;
  int pos = atomicAdd(&cursor[r], 1);
  srow[pos] = r; scol[pos] = c;
}

// Per 128-edge tile: h1 = relu(P[row]+Q'[col]) fp32 -> split bf16 hi/lo -> swizzled LDS;
// split-precision MFMA vs W2 hi/lo frags (a_hi*b_hi + a_hi*b_lo + a_lo*b_hi);
// relu(+b2) -> swizzled LDS f32; segmented sum by sorted row -> atomicAdd.
__global__ __launch_bounds__(256) void gemm2_k(const float* __restrict__ PQ,
                                               const int* __restrict__ srow, const int* __restrict__ scol,
                                               const unsigned short* __restrict__ w2h,
                                               const unsigned short* __restrict__ w2l,
                                               const float* __restrict__ b2,
                                               float* __restrict__ out) {
  __shared__ __attribute__((aligned(16))) char smem[65536];
  float* h2 = (float*)smem;
  int tid = threadIdx.x, lane = tid & 63, wave = tid >> 6;
  int cg = wave & 1, eg = wave >> 1;
  s16x8 bh[4][4], bl[4][4];
#pragma unroll
  for (int ct = 0; ct < 4; ++ct)
#pragma unroll
    for (int ks = 0; ks < 4; ++ks) {
      int off = (((cg * 4 + ct) * 4 + ks) * 64 + lane) * 8;
      bh[ct][ks] = *(const s16x8*)(w2h + off);
      bl[ct][ks] = *(const s16x8*)(w2l + off);
    }
  float b2r[4];
#pragma unroll
  for (int ct = 0; ct < 4; ++ct) b2r[ct] = b2[cg * 64 + ct * 16 + (lane & 15)];

  for (int tile = blockIdx.x; tile < NEDGE / 128; tile += gridDim.x) {
    int base = tile * 128;
    {
      int e_in = tid >> 1, c0 = (tid & 1) * 64;
      int e = base + e_in;
      int row = srow[e], colc = scol[e];
      const float* Pp = PQ + (size_t)row * 256 + c0;
      const float* Qp = PQ + (size_t)colc * 256 + 128 + c0;
#pragma unroll
      for (int cc = 0; cc < 64; cc += 8) {
        f32x4 p0 = *(const f32x4*)(Pp + cc);
        f32x4 p1 = *(const f32x4*)(Pp + cc + 4);
        f32x4 q0 = *(const f32x4*)(Qp + cc);
        f32x4 q1 = *(const f32x4*)(Qp + cc + 4);
        s16x8 hv, lv;
#pragma unroll
        for (int k2 = 0; k2 < 4; ++k2) {
          float sv = p0[k2] + q0[k2];
          sv = sv > 0.f ? sv : 0.f;
          unsigned short hi = f2bf(sv);
          hv[k2] = (short)hi; lv[k2] = (short)f2bf(sv - bf2f(hi));
          float sw = p1[k2] + q1[k2];
          sw = sw > 0.f ? sw : 0.f;
          unsigned short hj = f2bf(sw);
          hv[4 + k2] = (short)hj; lv[4 + k2] = (short)f2bf(sw - bf2f(hj));
        }
        int byteoff = e_in * 256 + (((c0 + cc) * 2) ^ ((e_in & 7) << 4));
        *(s16x8*)(smem + byteoff) = hv;
        *(s16x8*)(smem + 32768 + byteoff) = lv;
      }
    }
    __syncthreads();
    f32x4 acc[4][4];
#pragma unroll
    for (int rt = 0; rt < 4; ++rt)
#pragma unroll
      for (int ct = 0; ct < 4; ++ct) acc[rt][ct] = (f32x4){0.f, 0.f, 0.f, 0.f};
#pragma unroll
    for (int rt = 0; rt < 4; ++rt) {
      int rowL = eg * 64 + rt * 16 + (lane & 15);
#pragma unroll
      for (int ks = 0; ks < 4; ++ks) {
        int byteoff = rowL * 256 + ((16 * (lane >> 4) + 64 * ks) ^ ((rowL & 7) << 4));
        s16x8 a_hi = *(const s16x8*)(smem + byteoff);
        s16x8 a_lo = *(const s16x8*)(smem + 32768 + byteoff);
#pragma unroll
        for (int ct = 0; ct < 4; ++ct) {
          acc[rt][ct] = __builtin_amdgcn_mfma_f32_16x16x32_bf16(a_hi, bh[ct][ks], acc[rt][ct], 0, 0, 0);
          acc[rt][ct] = __builtin_amdgcn_mfma_f32_16x16x32_bf16(a_hi, bl[ct][ks], acc[rt][ct], 0, 0, 0);
          acc[rt][ct] = __builtin_amdgcn_mfma_f32_16x16x32_bf16(a_lo, bh[ct][ks], acc[rt][ct], 0, 0, 0);
        }
      }
    }
    __syncthreads();
#pragma unroll
    for (int rt = 0; rt < 4; ++rt)
#pragma unroll
      for (int ct = 0; ct < 4; ++ct) {
        int col = cg * 64 + ct * 16 + (lane & 15);
#pragma unroll
        for (int r = 0; r < 4; ++r) {
          int row_in = eg * 64 + rt * 16 + (lane >> 4) * 4 + r;
          float v = acc[rt][ct][r] + b2r[ct];
          v = v > 0.f ? v : 0.f;
          int gq = (row_in >> 2) & 3;
          h2[row_in * 128 + (col ^ (gq << 2) ^ ((gq & 1) << 4))] = v;
        }
      }
    __syncthreads();
    {
      int col = tid & 127, estart = (tid >> 7) * 64;
      float a = 0.f;
      int prev = srow[base + estart];
#pragma unroll 8
      for (int e2 = estart; e2 < estart + 64; ++e2) {
        int r2 = srow[base + e2];
        if (r2 != prev) { atomicAdd(out + (size_t)prev * 128 + col, a); a = 0.f; prev = r2; }
        int gq = (e2 >> 2) & 3;
        a += h2[e2 * 128 + (col ^ (gq << 2) ^ ((gq & 1) << 4))];
      }
      atomicAdd(out + (size_t)prev * 128 + col, a);
    }
    __syncthreads();
  }
}

__global__ void final_k(float* __restrict__ out, const int* __restrict__ counts) {
  int idx = blockIdx.x * 256 + threadIdx.x;
  int n = idx >> 7;
  int c = counts[n];
  c = c > 0 ? c : 1;
  out[idx] = out[idx] / (float)c;
}

extern "C" void kernel_launch(void* const* d_in, const int* in_sizes, int n_in,
                              void* d_out, int out_size, void* d_ws, size_t ws_size,
                              hipStream_t stream) {
  const float* x = (const float*)d_in[0];
  const float* W1 = (const float*)d_in[2];
  const float* b1 = (const float*)d_in[3];
  const float* W2 = (const float*)d_in[4];
  const float* b2 = (const float*)d_in[5];
  float* out = (float*)d_out;
  char* ws = (char*)d_ws;

  float* PQ = (float*)(ws + 0);                            // 67,108,864 B
  float* sq = (float*)(ws + 67108864);                     //    262,144 B
  int* nbr = (int*)(ws + 67371008);                        //  4,194,304 B
  int* counts = (int*)(ws + 71565312);                     //    262,144 B
  int* cursor = (int*)(ws + 71827456);                     //    262,144 B
  int* srow = (int*)(ws + 72089600);                       //  4,194,304 B
  int* scol = (int*)(ws + 76283904);                       //  4,194,304 B
  unsigned short* w2h = (unsigned short*)(ws + 80478208);  //     32,768 B
  unsigned short* w2l = (unsigned short*)(ws + 80510976);  //     32,768 B
  double* sq64 = (double*)(ws + 80543744);                 //    524,288 B  (end 81,068,032)

  hipMemsetAsync(d_out, 0, (size_t)out_size * sizeof(float), stream);
  hipMemsetAsync(counts, 0, (size_t)N_NODES * sizeof(int), stream);
  prep_weights_k<<<1, 256, 0, stream>>>(W2, w2h, w2l);
  prep_sq_k<<<N_NODES / 256, 256, 0, stream>>>(x, sq, sq64);
  prep_pq_k<<<N_NODES / 16, 256, 0, stream>>>(x, W1, b1, PQ);
  knn_k<<<N_NODES / 256, 256, 0, stream>>>(x, sq, sq64, nbr, counts);
  scan_k<<<1, 256, 0, stream>>>(counts, cursor);
  scatter_k<<<NEDGE / 256, 256, 0, stream>>>(nbr, cursor, srow, scol);
  gemm2_k<<<512, 256, 0, stream>>>(PQ, srow, scol, w2h, w2l, b2, out);
  final_k<<<(N_NODES * HDIM) / 256, 256, 0, stream>>>(out, counts);
}